// Round 3
// baseline (303.578 us; speedup 1.0000x reference)
//
#include <hip/hip_runtime.h>
#include <stdint.h>

typedef __bf16 bf16x8 __attribute__((ext_vector_type(8)));
typedef float f32x4 __attribute__((ext_vector_type(4)));

// ---- workspace byte offsets ----
#define OFF_GWT   62914560u    // (g*W)^T bf16 per level [512][C]
#define OFF_H     66846720u    // h bf16 per level [8192][512]
#define OFF_U     100679680u   // 4*512 f32 (zeroed, atomic-accumulated)
#define OFF_GG    100687872u
#define OFF_BB    100696064u
#define OFF_SCAL  100704256u   // [0..3] sproto, [4..7] sqproto (zeroed)
#define WS_TOTAL  100719872u

__host__ __device__ __forceinline__ size_t gwt_off(int l) {
  return (size_t)262144u * (size_t)((1u << l) - 1u);
}

__device__ __forceinline__ unsigned short f2bf(float x) {
  return (unsigned short)((__float_as_uint(x) + 0x8000u) >> 16);
}
__device__ __forceinline__ unsigned pack2(float a, float b) {
  return ((__float_as_uint(a) + 0x8000u) >> 16) |
         ((__float_as_uint(b) + 0x8000u) & 0xffff0000u);
}
__device__ __forceinline__ void async_load16(const void* g, void* l) {
  __builtin_amdgcn_global_load_lds((const __attribute__((address_space(1))) void*)g,
                                   (__attribute__((address_space(3))) void*)l,
                                   16, 0, 0);
}

struct PrepArgs {
  const float* pooled[4];
  const float* proto[4];
  const float* W[4];
  const float* g[4];
  const float* beta[4];
  const float* bias[4];
  const float* text;
  const float* lsc;
  char* ws;
};

// ================= wtrans: W-slab transpose + Gsum/Bsum/u + pmean/scal =================
// 480 blocks, each a 64(j) x 128(d) slab. Bottom-half blocks compute their own
// pmean chunk from proto (64 rows x 64 cols = 16 KB); dchunk==0 blocks also
// atomic-add the proto sum/sumsq into scal for the LN statistics.
__global__ __launch_bounds__(256) void wtrans(PrepArgs A) {
  __shared__ unsigned short tile[128][66];     // padded: 2-way-only banking
  __shared__ float redG[4][128], redB[4][128], redU[4][128];
  __shared__ float gsh[64], bsh[64], psh[64];
  __shared__ float redP[4][64];
  int t = threadIdx.x, bid = blockIdx.x;
  int l, idl;
  if (bid < 256)      { l = 3; idl = bid; }
  else if (bid < 384) { l = 2; idl = bid - 256; }
  else if (bid < 448) { l = 1; idl = bid - 384; }
  else                { l = 0; idl = bid - 448; }
  int C = 256 << l;
  int sid = idl >> 2, dchunk = idl & 3;
  int j0 = sid * 64, d0 = dchunk * 128;
  bool top = (j0 < C);
  int w = t >> 6, L = t & 63;
  float* scal = (float*)(A.ws + OFF_SCAL);

  if (t < 64) {
    gsh[t] = A.g[l][j0 + t];
    bsh[t] = A.beta[l][j0 + t];
  }
  if (!top) {
    // local pmean over the 64 proto rows for this block's 64 columns
    const float* pr = A.proto[l];
    int cb0 = j0 - C;
    float s = 0.f;
#pragma unroll
    for (int r = 0; r < 16; ++r) s += pr[(size_t)(w * 16 + r) * C + cb0 + L];
    redP[w][L] = s;
  }
  __syncthreads();
  if (!top) {
    if (t < 64) {
      float pmv = (redP[0][t] + redP[1][t] + redP[2][t] + redP[3][t]) * (1.0f / 64.0f);
      psh[t] = pmv * gsh[t];
      if (dchunk == 0) {
        float s1 = pmv, s2 = pmv * pmv;
#pragma unroll
        for (int off = 1; off < 64; off <<= 1) {
          s1 += __shfl_xor(s1, off);
          s2 += __shfl_xor(s2, off);
        }
        if (t == 0) {
          atomicAdd(&scal[l], s1);
          atomicAdd(&scal[4 + l], s2);
        }
      }
    }
    __syncthreads();
  }

  const float* W = A.W[l];
  float2 v[16];
#pragma unroll
  for (int r = 0; r < 16; ++r) {
    int j = j0 + w * 16 + r;
    v[r] = *(const float2*)(W + (size_t)j * 512 + d0 + 2 * L);
  }
  float gp0 = 0.f, gp1 = 0.f, bp0 = 0.f, bp1 = 0.f, up0 = 0.f, up1 = 0.f;
#pragma unroll
  for (int r = 0; r < 16; ++r) {
    int jl = w * 16 + r;
    float g = gsh[jl], b = bsh[jl];
    gp0 = fmaf(g, v[r].x, gp0); gp1 = fmaf(g, v[r].y, gp1);
    bp0 = fmaf(b, v[r].x, bp0); bp1 = fmaf(b, v[r].y, bp1);
    if (top) {
      tile[2 * L][jl] = f2bf(g * v[r].x);
      tile[2 * L + 1][jl] = f2bf(g * v[r].y);
    } else {
      float p = psh[jl];
      up0 = fmaf(p, v[r].x, up0); up1 = fmaf(p, v[r].y, up1);
    }
  }
  redG[w][2 * L] = gp0; redG[w][2 * L + 1] = gp1;
  redB[w][2 * L] = bp0; redB[w][2 * L + 1] = bp1;
  if (!top) { redU[w][2 * L] = up0; redU[w][2 * L + 1] = up1; }
  __syncthreads();

  if (t < 128) {
    int d = l * 512 + d0 + t;
    float G = redG[0][t] + redG[1][t] + redG[2][t] + redG[3][t];
    float B = redB[0][t] + redB[1][t] + redB[2][t] + redB[3][t];
    atomicAdd(&((float*)(A.ws + OFF_GG))[d], G);
    atomicAdd(&((float*)(A.ws + OFF_BB))[d], B);
    if (!top) {
      float U = redU[0][t] + redU[1][t] + redU[2][t] + redU[3][t];
      atomicAdd(&((float*)(A.ws + OFF_U))[d], U);
    }
  }
  if (top) {
    // full slab coverage: 2 threads per d, 32 ushorts each -> 128 x 64 complete
    unsigned short* gwT = (unsigned short*)(A.ws + OFF_GWT + gwt_off(l));
    int d = t >> 1, jh = (t & 1) * 32;
    const unsigned* trow = (const unsigned*)&tile[d][jh];  // 4B-aligned
    uint4 q0 = make_uint4(trow[0], trow[1], trow[2], trow[3]);
    uint4 q1 = make_uint4(trow[4], trow[5], trow[6], trow[7]);
    uint4 q2 = make_uint4(trow[8], trow[9], trow[10], trow[11]);
    uint4 q3 = make_uint4(trow[12], trow[13], trow[14], trow[15]);
    uint4* dst = (uint4*)(gwT + (size_t)(d0 + d) * C + j0 + jh);
    dst[0] = q0; dst[1] = q1; dst[2] = q2; dst[3] = q3;
  }
}

// ================= gemm2: 128x128 bf16 GEMM, A reg-staged from f32 pooled =================
// A path: f32 global -> regs -> pack bf16 -> ds_write (XOR-swizzled k-granule);
// row sums/sumsq accumulate during packing (replaces the old aconv kernel).
// Next k-step's f32 loads issue after the pre-MFMA barrier and drain at the
// post-MFMA barrier, so they fly under the MFMA cluster (sched_barrier pins them).
struct G2Args {
  char* ws;
  const float* pooled[4];
  const float* bias[4];
};

__global__ __launch_bounds__(256, 3) void gemm2(G2Args A) {
  __shared__ __align__(16) char lds[18944];
  char* ws = A.ws;
  int t = threadIdx.x, bid = blockIdx.x;
  int l = 3 - (bid >> 8);          // heavy levels first
  int rb = (bid >> 2) & 63, cb = bid & 3;
  int C = 256 << l;
  int m0 = rb * 128, n0 = cb * 128;

  float* uArr  = (float*)(lds + 16384);
  float* gArr  = (float*)(lds + 16896);
  float* bArr  = (float*)(lds + 17408);
  float* rowM  = (float*)(lds + 17920);
  float* rowIS = (float*)(lds + 18432);
  const float* scal = (const float*)(ws + OFF_SCAL);

  if (t < 128) {
    int idx = l * 512 + n0 + t;
    uArr[t] = ((const float*)(ws + OFF_U))[idx];
    gArr[t] = ((const float*)(ws + OFF_GG))[idx];
    bArr[t] = ((const float*)(ws + OFF_BB))[idx] + A.bias[l][n0 + t];
  }

  int w = t >> 6, lane = t & 63, quad = lane >> 4, lc = lane & 15;
  const char* Bw = ws + OFF_GWT + gwt_off(l);
  const char* bP[2]; char* bD[2];
#pragma unroll
  for (int i = 0; i < 2; ++i) {
    int li = i * 256 + t;
    int rr = li >> 2, kq = li & 3;
    bP[i] = Bw + ((size_t)(n0 + rr) * C + kq * 8) * 2;
    bD[i] = lds + 8192 + i * 4096 + w * 1024;
  }
  // A staging: thread owns rows rA and 64+rA, k-granule kq (8 elems)
  int rA = t >> 2, kq = t & 3;
  const float* aG0 = A.pooled[l] + (size_t)(m0 + rA) * C + kq * 8;
  const float* aG1 = aG0 + (size_t)64 * C;
  int gsw = kq ^ ((rA >> 1) & 3);              // bank-spread swizzle (A only)
  char* aW0 = lds + rA * 64 + gsw * 16;
  char* aW1 = aW0 + 64 * 64;
  int wr = (w >> 1) * 64, wc = (w & 1) * 64;
  int ag = quad ^ (((wr + lc) >> 1) & 3);      // read-side inverse (same XOR)
  const char* aF = lds + (wr + lc) * 64 + ag * 16;
  const char* bF = lds + 8192 + (wc + lc) * 64 + quad * 16;

  f32x4 acc[4][4] = {};
  float s1a = 0.f, s2a = 0.f, s1b = 0.f, s2b = 0.f;
  f32x4 a0 = *(const f32x4*)aG0, a1 = *(const f32x4*)(aG0 + 4);
  f32x4 a2 = *(const f32x4*)aG1, a3 = *(const f32x4*)(aG1 + 4);
  for (int k0 = 0; k0 < C; k0 += 32) {
    if (k0) __syncthreads();
    async_load16(bP[0], bD[0]); async_load16(bP[1], bD[1]);
    bP[0] += 64; bP[1] += 64;
    *(uint4*)aW0 = make_uint4(pack2(a0[0], a0[1]), pack2(a0[2], a0[3]),
                              pack2(a1[0], a1[1]), pack2(a1[2], a1[3]));
    *(uint4*)aW1 = make_uint4(pack2(a2[0], a2[1]), pack2(a2[2], a2[3]),
                              pack2(a3[0], a3[1]), pack2(a3[2], a3[3]));
    s1a += ((a0[0] + a0[1]) + (a0[2] + a0[3])) + ((a1[0] + a1[1]) + (a1[2] + a1[3]));
    s2a = fmaf(a0[0], a0[0], s2a); s2a = fmaf(a0[1], a0[1], s2a);
    s2a = fmaf(a0[2], a0[2], s2a); s2a = fmaf(a0[3], a0[3], s2a);
    s2a = fmaf(a1[0], a1[0], s2a); s2a = fmaf(a1[1], a1[1], s2a);
    s2a = fmaf(a1[2], a1[2], s2a); s2a = fmaf(a1[3], a1[3], s2a);
    s1b += ((a2[0] + a2[1]) + (a2[2] + a2[3])) + ((a3[0] + a3[1]) + (a3[2] + a3[3]));
    s2b = fmaf(a2[0], a2[0], s2b); s2b = fmaf(a2[1], a2[1], s2b);
    s2b = fmaf(a2[2], a2[2], s2b); s2b = fmaf(a2[3], a2[3], s2b);
    s2b = fmaf(a3[0], a3[0], s2b); s2b = fmaf(a3[1], a3[1], s2b);
    s2b = fmaf(a3[2], a3[2], s2b); s2b = fmaf(a3[3], a3[3], s2b);
    __syncthreads();
    if (k0 + 32 < C) {
      aG0 += 32; aG1 += 32;
      a0 = *(const f32x4*)aG0; a1 = *(const f32x4*)(aG0 + 4);
      a2 = *(const f32x4*)aG1; a3 = *(const f32x4*)(aG1 + 4);
    }
    __builtin_amdgcn_sched_barrier(0);
    bf16x8 av[4];
#pragma unroll
    for (int rt = 0; rt < 4; ++rt) av[rt] = *(const bf16x8*)(aF + rt * 1024);
#pragma unroll
    for (int ct = 0; ct < 4; ++ct) {
      bf16x8 bv = *(const bf16x8*)(bF + ct * 1024);
#pragma unroll
      for (int rt = 0; rt < 4; ++rt)
        acc[rt][ct] = __builtin_amdgcn_mfma_f32_16x16x32_bf16(av[rt], bv, acc[rt][ct], 0, 0, 0);
    }
  }

  // finish row stats: reduce the 4 kq-granule partials per row
#pragma unroll
  for (int off = 1; off < 4; off <<= 1) {
    s1a += __shfl_xor(s1a, off); s2a += __shfl_xor(s2a, off);
    s1b += __shfl_xor(s1b, off); s2b += __shfl_xor(s2b, off);
  }
  if ((t & 3) == 0) {
    float inv2C = 1.0f / (float)(2 * C);
    float spro = scal[l], sqpro = scal[4 + l];
    float mra = (s1a + spro) * inv2C;
    rowM[rA] = mra;
    rowIS[rA] = rsqrtf((s2a + sqpro) * inv2C - mra * mra + 1e-5f);
    float mrb = (s1b + spro) * inv2C;
    rowM[64 + rA] = mrb;
    rowIS[64 + rA] = rsqrtf((s2b + sqpro) * inv2C - mrb * mrb + 1e-5f);
  }
  __syncthreads();

  // epilogue: h = relu((acc + u - m*G)*invs + B) -> bf16 store
  char* Hl = ws + OFF_H + (size_t)l * 8388608;
#pragma unroll
  for (int rt = 0; rt < 4; ++rt) {
#pragma unroll
    for (int ct = 0; ct < 4; ++ct) {
      int nl = wc + ct * 16 + lc;
      float uu = uArr[nl], gg = gArr[nl], bb = bArr[nl];
      f32x4 a = acc[rt][ct];
#pragma unroll
      for (int reg = 0; reg < 4; ++reg) {
        int ml = wr + rt * 16 + quad * 4 + reg;
        float h = fmaf(a[reg] + uu - rowM[ml] * gg, rowIS[ml], bb);
        h = fmaxf(h, 0.f);
        float hp = __shfl_xor(h, 1);
        if (!(lc & 1)) {
          unsigned pkv = pack2(h, hp);
          *(unsigned*)(Hl + ((size_t)(m0 + ml) * 512 + n0 + nl) * 2) = pkv;
        }
      }
    }
  }
}

// ================= postK: text norm + l2norm + text dots + softmax =================
__global__ __launch_bounds__(256) void postK(const char* ws, const float* text,
                                             const float* lsc, float* out) {
  __shared__ float textL[4096];
  int t = threadIdx.x, b = blockIdx.x;
  {
    // normalize the 8 text rows locally: 32 lanes per row
    int gq = t >> 5, lq = t & 31;
    float v[16];
    float pa = 0.f;
#pragma unroll
    for (int i = 0; i < 16; ++i) {
      v[i] = text[gq * 512 + lq + 32 * i];
      pa = fmaf(v[i], v[i], pa);
    }
#pragma unroll
    for (int off = 1; off < 32; off <<= 1) pa += __shfl_xor(pa, off);
    float inv = 1.0f / fmaxf(sqrtf(pa), 1e-12f);
#pragma unroll
    for (int i = 0; i < 16; ++i) textL[gq * 512 + lq + 32 * i] = v[i] * inv;
  }
  __syncthreads();
  float scale = fmaxf(lsc[0], 1e-4f) * 0.04419417382415922f;  // 1/sqrt(512)
  int row = b * 16 + (t >> 4), q = t & 15;
  float lg[4][8];
#pragma unroll
  for (int l = 0; l < 4; ++l) {
    const uint4* hp = (const uint4*)(ws + OFF_H + (size_t)l * 8388608 +
                                     ((size_t)row * 512 + q * 32) * 2);
    float np = 0.f;
    float dp[8] = {};
#pragma unroll
    for (int ch = 0; ch < 4; ++ch) {
      uint4 u = hp[ch];
      int d0 = q * 32 + ch * 8;
      unsigned uw[4] = {u.x, u.y, u.z, u.w};
#pragma unroll
      for (int p = 0; p < 4; ++p) {
        float v0 = __uint_as_float(uw[p] << 16);
        float v1 = __uint_as_float(uw[p] & 0xffff0000u);
        int dd = d0 + p * 2;
        np = fmaf(v0, v0, np);
        np = fmaf(v1, v1, np);
#pragma unroll
        for (int k = 0; k < 8; ++k) {
          dp[k] = fmaf(v0, textL[k * 512 + dd], dp[k]);
          dp[k] = fmaf(v1, textL[k * 512 + dd + 1], dp[k]);
        }
      }
    }
#pragma unroll
    for (int off = 1; off < 16; off <<= 1) {
      np += __shfl_xor(np, off);
#pragma unroll
      for (int k = 0; k < 8; ++k) dp[k] += __shfl_xor(dp[k], off);
    }
    float innorm = scale / fmaxf(sqrtf(np), 1e-12f);
#pragma unroll
    for (int k = 0; k < 8; ++k) lg[l][k] = dp[k] * innorm;
  }
  if (q == 0) {
    float4* op = (float4*)out + (size_t)row * 8;
#pragma unroll
    for (int k = 0; k < 8; ++k) {
      float a = lg[0][k], b2 = lg[1][k], c = lg[2][k], d = lg[3][k];
      float mx = fmaxf(fmaxf(a, b2), fmaxf(c, d));
      float e0 = __expf(a - mx), e1 = __expf(b2 - mx);
      float e2 = __expf(c - mx), e3 = __expf(d - mx);
      float inv = 1.0f / (e0 + e1 + e2 + e3);
      op[k] = make_float4(e0 * inv, e1 * inv, e2 * inv, e3 * inv);
    }
  }
}

extern "C" void kernel_launch(void* const* d_in, const int* in_sizes, int n_in,
                              void* d_out, int out_size, void* d_ws, size_t ws_size,
                              hipStream_t stream) {
  (void)n_in; (void)out_size;
  if (ws_size < (size_t)WS_TOTAL) return;  // loud failure: output stays poisoned
  char* ws = (char*)d_ws;
  bool dict = (in_sizes[1] == 64 * 256);
  PrepArgs pa;
  for (int l = 0; l < 4; ++l) {
    if (dict) {
      pa.pooled[l] = (const float*)d_in[6 * l + 0];
      pa.proto[l]  = (const float*)d_in[6 * l + 1];
      pa.g[l]      = (const float*)d_in[6 * l + 2];
      pa.beta[l]   = (const float*)d_in[6 * l + 3];
      pa.W[l]      = (const float*)d_in[6 * l + 4];
      pa.bias[l]   = (const float*)d_in[6 * l + 5];
    } else {
      pa.pooled[l] = (const float*)d_in[l];
      pa.proto[l]  = (const float*)d_in[4 + l];
      pa.g[l]      = (const float*)d_in[8 + l];
      pa.beta[l]   = (const float*)d_in[12 + l];
      pa.W[l]      = (const float*)d_in[16 + l];
      pa.bias[l]   = (const float*)d_in[20 + l];
    }
  }
  pa.text = (const float*)d_in[24];
  pa.lsc = (const float*)d_in[25];
  pa.ws = ws;

  // zero the atomic accumulators (U/GG/BB/SCAL are contiguous)
  hipMemsetAsync(ws + OFF_U, 0, 3 * 8192 + 256, stream);
  wtrans<<<480, 256, 0, stream>>>(pa);

  G2Args g2;
  g2.ws = ws;
  for (int l = 0; l < 4; ++l) {
    g2.pooled[l] = pa.pooled[l];
    g2.bias[l] = pa.bias[l];
  }
  gemm2<<<1024, 256, 0, stream>>>(g2);
  postK<<<512, 256, 0, stream>>>(ws, pa.text, pa.lsc, (float*)d_out);
}